// Round 5
// baseline (261.846 us; speedup 1.0000x reference)
//
#include <hip/hip_runtime.h>

// GNN: 2x GCNConv(relu) + mean-pool + MLP head.
// Sizes fixed: N=50000, E=800000, F_IN=256, H=64, NG=64, NC=4.
//
// R9: hs/hb bf16, f32 accumulate. R11: dual-edge packed gather.
// R13: GEMMs on bf16 MFMA (16x16x32), split-bf16 hi/lo, swizzled LDS.
// R15: poolhead last-block fusion REGRESSED (threadfence stall) -> reverted.
// R16: gemm2 fused into agg1 (per-wave 64x64 VALU matmul) — counters showed
//      fused agg1 == plain agg2 == 42.4us -> fusion free, gather latency-bound
//      (HBM 12%, VALU 33%, occ 65%: nothing saturated).
// R17 (this round): k_agg restructured for MLP:
//      - one coalesced csr_src load per 32-edge batch (lane&31), replacing
//        8 broadcast loads + serialized 8/4/2/1 tails;
//      - indices distributed to edge-pair owners via __shfl (register-only);
//      - all <=16 gathers of the batch issued back-to-back, predicated
//        (invalid slots clamp to own row, adds cndmask'd out);
//      - deg<=32 (99.99% of Poisson(16)) = single batch, 2 dependent
//        latencies per node instead of ~4 chained groups.

#define TPB 256
#define CHUNK_A 4096
#define BCAP 4608          // per-bucket staging capacity (mean 4096, +8 sigma)

typedef unsigned short bfu;
typedef __attribute__((ext_vector_type(8))) short s16x8;
typedef __attribute__((ext_vector_type(4))) float f32x4;

__device__ __forceinline__ float bf2f(bfu u) {
    union { unsigned u32; float f; } c; c.u32 = ((unsigned)u) << 16; return c.f;
}
__device__ __forceinline__ bfu f2bf(float f) {
    union { float f; unsigned u; } c; c.f = f;
    unsigned r = 0x7FFFu + ((c.u >> 16) & 1u);     // round-to-nearest-even
    return (bfu)((c.u + r) >> 16);
}
__device__ __forceinline__ float blo(unsigned w) {
    union { unsigned u32; float f; } c; c.u32 = w << 16; return c.f;
}
__device__ __forceinline__ float bhi(unsigned w) {
    union { unsigned u32; float f; } c; c.u32 = w & 0xFFFF0000u; return c.f;
}
__device__ __forceinline__ void split_bf(float x, bfu& h, bfu& l) {
    h = f2bf(x);
    l = f2bf(x - bf2f(h));
}

// ---------------- pass A: chunked bucket staging ----------------
// packed edge: (src<<8) | (dst & 255); requires n <= 65536, nbuck <= 256.

__global__ __launch_bounds__(TPB) void k_passA(const int* __restrict__ srcv,
                                               const int* __restrict__ dstv, int E,
                                               int* __restrict__ gcur,
                                               int* __restrict__ staged, int nbuck) {
    __shared__ int pk[CHUNK_A];
    __shared__ int hist[256];
    __shared__ int ebase[256];
    __shared__ int gbase[256];
    __shared__ int lcur[256];
    int t = threadIdx.x;
    int e0 = blockIdx.x * CHUNK_A;
    int e1 = e0 + CHUNK_A; if (e1 > E) e1 = E;

    hist[t] = 0; lcur[t] = 0;
    __syncthreads();
    for (int i = e0 + t; i < e1; i += TPB) atomicAdd(&hist[dstv[i] >> 8], 1);
    __syncthreads();
    int v = hist[t];
    ebase[t] = v;
    __syncthreads();
    for (int off = 1; off < 256; off <<= 1) {
        int u = (t >= off) ? ebase[t - off] : 0;
        __syncthreads();
        ebase[t] += u;
        __syncthreads();
    }
    ebase[t] -= v;
    if (t < nbuck && v > 0) gbase[t] = t * BCAP + atomicAdd(&gcur[t], v);
    __syncthreads();
    for (int i = e0 + t; i < e1; i += TPB) {
        int d = dstv[i];
        int s = srcv[i];
        int b = d >> 8;
        int r = atomicAdd(&lcur[b], 1);
        pk[ebase[b] + r] = (s << 8) | (d & 255);
    }
    __syncthreads();
    int wave = t >> 6, lane = t & 63;
    for (int b = wave; b < nbuck; b += 4) {
        int c = hist[b];
        int lb = ebase[b];
        int gb = gbase[b];
        for (int j = lane; j < c; j += 64) staged[gb + j] = pk[lb + j];
    }
}

// ---------------- pass B: per-bucket node sort + csr_off + dinv ----------------

__global__ __launch_bounds__(TPB) void k_passB(const int* __restrict__ staged,
                                               const int* __restrict__ gcur,
                                               int* __restrict__ csr_off,
                                               int* __restrict__ csr_src,
                                               float* __restrict__ dinv,
                                               int n, int nbuck) {
    __shared__ int pk[BCAP];
    __shared__ int soff[256];
    __shared__ int hist[256];
    __shared__ int nbase[256];
    __shared__ int cur[256];
    int b = blockIdx.x;
    int n0 = b << 8;
    int n1 = n0 + 256; if (n1 > n) n1 = n;
    int cnt = gcur[b];
    int t = threadIdx.x;

    int cv = (t < nbuck) ? gcur[t] : 0;
    soff[t] = cv;
    hist[t] = 0; cur[t] = 0;
    __syncthreads();
    for (int off = 1; off < 256; off <<= 1) {
        int u = (t >= off) ? soff[t - off] : 0;
        __syncthreads();
        soff[t] += u;
        __syncthreads();
    }
    int base = soff[b] - cnt;   // exclusive prefix at bucket b

    for (int i = t; i < cnt; i += TPB) pk[i] = staged[b * BCAP + i];
    __syncthreads();
    for (int i = t; i < cnt; i += TPB) atomicAdd(&hist[pk[i] & 255], 1);
    __syncthreads();
    int v = hist[t];
    nbase[t] = v;
    __syncthreads();
    for (int off = 1; off < 256; off <<= 1) {
        int u = (t >= off) ? nbase[t - off] : 0;
        __syncthreads();
        nbase[t] += u;
        __syncthreads();
    }
    nbase[t] -= v;
    if (n0 + t < n1) {
        csr_off[n0 + t] = base + nbase[t];
        dinv[n0 + t] = rsqrtf((float)(v + 1));   // +1 self loop
    }
    if (b == nbuck - 1 && t == 0) csr_off[n] = base + cnt;
    __syncthreads();
    for (int i = t; i < cnt; i += TPB) {
        int p = pk[i];
        int dloc = p & 255;
        int r = atomicAdd(&cur[dloc], 1);
        csr_src[base + nbase[dloc] + r] = p >> 8;
    }
}

// ---------------- GEMM (MFMA): C[r][j] = dinv[r] * sum_k A[r][k] * W[k][j] ----------------
// Block = 128 rows x 64 cols, 4 waves; wave = 32 rows x 64 cols
// (2 row-tiles x 4 col-tiles of 16x16, K-step 32). K-chunk 64 in LDS.
// f32 A: split-bf16 hi/lo planes, products hi*hi + hi*lo + lo*hi.
// LDS XOR swizzle: element k ^ ((rc&7)<<3), 16B-granule permutation.
// C/D map (m89-verified): col=lane&15, row=(lane>>4)*4+reg.

__device__ __forceinline__ int swz(int rc, int k) {
    return rc * 64 + (k ^ ((rc & 7) << 3));
}

template <int K, bool BF16A>
__global__ __launch_bounds__(TPB) void k_gemm(const void* __restrict__ Av,
                                              const float* __restrict__ W,
                                              const float* __restrict__ dinv,
                                              bfu* __restrict__ C, int n) {
    __shared__ __align__(16) ushort Ah[128 * 64];
    __shared__ __align__(16) ushort Al[BF16A ? 64 : 128 * 64];
    __shared__ __align__(16) ushort Bh[64 * 64];
    __shared__ __align__(16) ushort Bl[64 * 64];

    const int t = threadIdx.x;
    const int wave = t >> 6, lane = t & 63;
    const int rbase = blockIdx.x * 128;

    f32x4 acc[2][4];
#pragma unroll
    for (int i = 0; i < 2; i++)
#pragma unroll
        for (int j = 0; j < 4; j++) acc[i][j] = {0.f, 0.f, 0.f, 0.f};

    for (int kc = 0; kc < K; kc += 64) {
        // ---- stage B: W chunk [64k x 64c] -> transposed bf16 hi/lo ----
        {
            int c = t & 63;
            int kg = (t >> 6) << 4;   // 16 k's per wave
#pragma unroll
            for (int q = 0; q < 4; q++) {
                ushort4 h4, l4;
#pragma unroll
                for (int j = 0; j < 4; j++) {
                    float w = W[(size_t)(kc + kg + q * 4 + j) * 64 + c];
                    bfu hh, ll; split_bf(w, hh, ll);
                    ((bfu*)&h4)[j] = hh;
                    ((bfu*)&l4)[j] = ll;
                }
                *(ushort4*)&Bh[swz(c, kg + q * 4)] = h4;
                *(ushort4*)&Bl[swz(c, kg + q * 4)] = l4;
            }
        }
        // ---- stage A chunk [128r x 64k] ----
        if (!BF16A) {
            const float* A = (const float*)Av;
#pragma unroll
            for (int q = 0; q < 8; q++) {
                int idx = q * 256 + t;
                int row = idx >> 4;
                int k4 = (idx & 15) << 2;
                int r = rbase + row;
                float4 xv = make_float4(0.f, 0.f, 0.f, 0.f);
                if (r < n) xv = *(const float4*)&A[(size_t)r * K + kc + k4];
                ushort4 h4, l4;
                split_bf(xv.x, ((bfu*)&h4)[0], ((bfu*)&l4)[0]);
                split_bf(xv.y, ((bfu*)&h4)[1], ((bfu*)&l4)[1]);
                split_bf(xv.z, ((bfu*)&h4)[2], ((bfu*)&l4)[2]);
                split_bf(xv.w, ((bfu*)&h4)[3], ((bfu*)&l4)[3]);
                *(ushort4*)&Ah[swz(row, k4)] = h4;
                *(ushort4*)&Al[swz(row, k4)] = l4;
            }
        } else {
            const bfu* A = (const bfu*)Av;
#pragma unroll
            for (int q = 0; q < 4; q++) {
                int idx = q * 256 + t;
                int row = idx >> 3;
                int k8 = (idx & 7) << 3;
                int r = rbase + row;
                uint4 v = make_uint4(0u, 0u, 0u, 0u);
                if (r < n) v = *(const uint4*)(A + (size_t)r * 64 + k8);
                *(uint2*)&Ah[swz(row, k8)]     = make_uint2(v.x, v.y);
                *(uint2*)&Ah[swz(row, k8 + 4)] = make_uint2(v.z, v.w);
            }
        }
        __syncthreads();

        // ---- MFMA compute ----
        const int rl = lane & 15;            // M/N index within tile
        const int kg8 = (lane >> 4) << 3;    // k offset of this lane group
#pragma unroll
        for (int ks = 0; ks < 2; ks++) {
            int k0 = ks * 32 + kg8;
            s16x8 a_h[2], a_l[2], b_h[4], b_l[4];
#pragma unroll
            for (int rt = 0; rt < 2; rt++) {
                int row = wave * 32 + rt * 16 + rl;
                a_h[rt] = *(const s16x8*)&Ah[swz(row, k0)];
                if (!BF16A) a_l[rt] = *(const s16x8*)&Al[swz(row, k0)];
            }
#pragma unroll
            for (int ct = 0; ct < 4; ct++) {
                int cc = ct * 16 + rl;
                b_h[ct] = *(const s16x8*)&Bh[swz(cc, k0)];
                b_l[ct] = *(const s16x8*)&Bl[swz(cc, k0)];
            }
#pragma unroll
            for (int rt = 0; rt < 2; rt++)
#pragma unroll
                for (int ct = 0; ct < 4; ct++) {
                    acc[rt][ct] = __builtin_amdgcn_mfma_f32_16x16x32_bf16(
                        a_h[rt], b_h[ct], acc[rt][ct], 0, 0, 0);
                    acc[rt][ct] = __builtin_amdgcn_mfma_f32_16x16x32_bf16(
                        a_h[rt], b_l[ct], acc[rt][ct], 0, 0, 0);
                    if (!BF16A)
                        acc[rt][ct] = __builtin_amdgcn_mfma_f32_16x16x32_bf16(
                            a_l[rt], b_h[ct], acc[rt][ct], 0, 0, 0);
                }
        }
        __syncthreads();
    }

    // ---- epilogue ----
    const int rl = lane & 15;
    const int rq = (lane >> 4) << 2;
#pragma unroll
    for (int rt = 0; rt < 2; rt++) {
#pragma unroll
        for (int reg = 0; reg < 4; reg++) {
            int r = rbase + wave * 32 + rt * 16 + rq + reg;
            if (r < n) {
                float d = dinv[r];
#pragma unroll
                for (int ct = 0; ct < 4; ct++) {
                    C[(size_t)r * 64 + ct * 16 + rl] = f2bf(acc[rt][ct][reg] * d);
                }
            }
        }
    }
}

// ---------------- Aggregation (R17): batch-issued predicated gather ----------------
// Wave = 1 node. 2 halves of 32 lanes; lane handles 2 features (unsigned).
// Per 32-edge batch: ONE coalesced csr_src load (lane&31) -> __shfl
// distributes indices -> up to 16 gathers issued back-to-back, predicated
// (invalid slots clamp to own row; adds cndmask'd). deg<=32 => 1 batch.
// FUSE: per-wave 64x64 W2 matmul on the relu'd row (gemm2 fusion, R16).

#define AGG_ISSUE8(G) \
    { \
        _Pragma("unroll") \
        for (int i = 0; i < 8; i++) { \
            int e = 2 * ((G) * 8 + i) + half; \
            int s = __shfl(myidx, e); \
            gb[(G) * 8 + i] = *(const unsigned*)(hs + (size_t)((e < rem) ? s : node) * 64 + fl); \
        } \
    }

#define AGG_ADD8(G) \
    { \
        _Pragma("unroll") \
        for (int i = 0; i < 8; i++) { \
            int e = 2 * ((G) * 8 + i) + half; \
            unsigned g = gb[(G) * 8 + i]; \
            ax += (e < rem) ? blo(g) : 0.f; \
            ay += (e < rem) ? bhi(g) : 0.f; \
        } \
    }

template <bool FUSE>
__global__ __launch_bounds__(TPB) void k_agg(const bfu* __restrict__ hs,
                                             const int* __restrict__ csr_off,
                                             const int* __restrict__ csr_src,
                                             const float* __restrict__ dinv,
                                             const float* __restrict__ bias,
                                             const float* __restrict__ W2,
                                             bfu* __restrict__ out, int n) {
    __shared__ float rowbuf[4][64];
    int wv = threadIdx.x >> 6;
    int node = blockIdx.x * 4 + wv;
    int lane = threadIdx.x & 63;
    int half = lane >> 5;          // 0 or 1
    int fl = (lane & 31) * 2;      // feature pair base
    if (node >= n) return;
    int p0 = csr_off[node];
    int p1 = csr_off[node + 1];
    int deg = p1 - p0;
    float d = dinv[node];          // issue early, needed late

    // self-loop row (independent, issued before index load)
    unsigned gself = *(const unsigned*)(hs + (size_t)node * 64 + fl);

    float ax = 0.f, ay = 0.f;
    for (int base = 0; base < deg; base += 32) {   // 1 iteration for deg<=32 (99.99%)
        int rem = deg - base;
        int li = p0 + base + (lane & 31);
        int myidx = (li < p1) ? csr_src[li] : node;
        unsigned gb[16];
        AGG_ISSUE8(0)
        if (rem > 16) AGG_ISSUE8(1)
        AGG_ADD8(0)
        if (rem > 16) AGG_ADD8(1)
    }
    if (half == 0) { ax += blo(gself); ay += bhi(gself); }

    // combine halves (same fl in lane and lane^32)
    ax += __shfl_xor(ax, 32);
    ay += __shfl_xor(ay, 32);

    float vx = fmaxf(d * ax + bias[fl + 0], 0.f);
    float vy = fmaxf(d * ay + bias[fl + 1], 0.f);
    if (!FUSE) {
        if (half == 0) {
            ushort2 o;
            o.x = f2bf(vx);
            o.y = f2bf(vy);
            *(ushort2*)(out + (size_t)node * 64 + fl) = o;
        }
    } else {
        // fused gemm2: out[node][lane] = f2bf(d * sum_k row[k] * W2[k][lane])
        if (half == 0) { rowbuf[wv][fl] = vx; rowbuf[wv][fl + 1] = vy; }
        __builtin_amdgcn_wave_barrier();   // ds_write before ds_read (same wave: HW in-order)
        float a = 0.f;
#pragma unroll 16
        for (int k = 0; k < 64; k++) a += rowbuf[wv][k] * W2[k * 64 + lane];
        out[(size_t)node * 64 + lane] = f2bf(d * a);
    }
}

// ---------------- Pool: sorted batch; uniform-chunk fast path (bf16 reads) ----------------

__global__ __launch_bounds__(TPB) void k_pool(const bfu* __restrict__ h,
                                              const int* __restrict__ batch, int n,
                                              float* __restrict__ gsum,
                                              int* __restrict__ gcnt) {
    const int CH = 16;
    int wid = blockIdx.x * 4 + (threadIdx.x >> 6);
    int lane = threadIdx.x & 63;
    int i0 = wid * CH;
    if (i0 >= n) return;
    int i1 = i0 + CH; if (i1 > n) i1 = n;
    int g0 = batch[i0];
    int g1 = batch[i1 - 1];
    if (g0 == g1) {
        float acc = 0.f;
#pragma unroll
        for (int i = 0; i < CH; i++) {
            int idx = i0 + i;
            if (idx < i1) acc += bf2f(h[(size_t)idx * 64 + lane]);
        }
        atomicAdd(&gsum[g0 * 64 + lane], acc);
        if (lane == 0) atomicAdd(&gcnt[g0], i1 - i0);
    } else {
        int cur = g0;
        float acc = 0.f;
        int cnt = 0;
        for (int i = i0; i < i1; i++) {
            int g = batch[i];
            if (g != cur) {
                atomicAdd(&gsum[cur * 64 + lane], acc);
                if (lane == 0) atomicAdd(&gcnt[cur], cnt);
                acc = 0.f; cnt = 0; cur = g;
            }
            acc += bf2f(h[(size_t)i * 64 + lane]);
            cnt++;
        }
        atomicAdd(&gsum[cur * 64 + lane], acc);
        if (lane == 0) atomicAdd(&gcnt[cur], cnt);
    }
}

// ---------------- Head, stage 1 ----------------

__global__ __launch_bounds__(TPB) void k_head1(const float* __restrict__ gsum,
                                               const int* __restrict__ gcnt,
                                               const float* __restrict__ fc1w,
                                               const float* __restrict__ fc1b,
                                               float* __restrict__ z) {
    int t = threadIdx.x;
    int g = blockIdx.x * 2 + (t >> 7);
    int o = t & 127;
    int c = gcnt[g]; if (c < 1) c = 1;
    float inv = 1.0f / (float)c;
    float a = fc1b[o];
#pragma unroll 16
    for (int j = 0; j < 64; j++) {
        float pj = gsum[g * 64 + j] * inv;
        a += pj * fc1w[j * 128 + o];
    }
    z[g * 128 + o] = fmaxf(a, 0.f);
}

// ---------------- Head, stage 2 ----------------

__global__ __launch_bounds__(TPB) void k_head2(const float* __restrict__ z,
                                               const float* __restrict__ fc2w,
                                               const float* __restrict__ fc2b,
                                               float* __restrict__ out) {
    int t = threadIdx.x;
    int g = t >> 2, c = t & 3;
    float a = fc2b[c];
#pragma unroll 16
    for (int o = 0; o < 128; o++) a += z[g * 128 + o] * fc2w[o * 4 + c];
    out[t] = a;
}

// ---------------- launch ----------------

extern "C" void kernel_launch(void* const* d_in, const int* in_sizes, int n_in,
                              void* d_out, int out_size, void* d_ws, size_t ws_size,
                              hipStream_t stream) {
    const float* x    = (const float*)d_in[0];
    const int*   ei   = (const int*)d_in[1];
    const int*   batch= (const int*)d_in[2];
    const float* W1   = (const float*)d_in[3];
    const float* b1   = (const float*)d_in[4];
    const float* W2   = (const float*)d_in[5];
    const float* b2   = (const float*)d_in[6];
    const float* fc1w = (const float*)d_in[7];
    const float* fc1b = (const float*)d_in[8];
    const float* fc2w = (const float*)d_in[9];
    const float* fc2b = (const float*)d_in[10];

    const int n = in_sizes[2];        // 50000
    const int E = in_sizes[1] / 2;    // 800000
    const int* srcv = ei;
    const int* dstv = ei + E;
    const int nbuck = (n + 255) >> 8; // 196 (must be <= 256)

    // workspace carve; zeroed region contiguous at front
    char* w = (char*)d_ws;
    int*   gcur   = (int*)w;            w += 256 * 4;
    int*   gcnt   = (int*)w;            w += 64 * 4;
    float* gsum   = (float*)w;          w += 64 * 64 * 4;
    size_t zbytes = (size_t)w - (size_t)d_ws;
    int*   csr_off= (int*)w;            w += (size_t)(n + 1) * 4;
    float* dinv   = (float*)w;          w += (size_t)n * 4;
    int*   csr_src= (int*)w;            w += (size_t)E * 4;
    int*   staged = (int*)w;            w += (size_t)nbuck * BCAP * 4;
    float* zbuf   = (float*)w;          w += 64 * 128 * 4;
    w = (char*)(((size_t)w + 255) & ~(size_t)255);
    bfu* hs = (bfu*)w;                  w += (size_t)n * 64 * 2;
    w = (char*)(((size_t)w + 255) & ~(size_t)255);
    bfu* hb = (bfu*)w;                  w += (size_t)n * 64 * 2;

    hipMemsetAsync(d_ws, 0, zbytes, stream);

    int gA = (E + CHUNK_A - 1) / CHUNK_A;   // 196
    k_passA<<<gA, TPB, 0, stream>>>(srcv, dstv, E, gcur, staged, nbuck);
    k_passB<<<nbuck, TPB, 0, stream>>>(staged, gcur, csr_off, csr_src, dinv, n, nbuck);

    int gRows = (n + 127) / 128;
    int gNode = (n + 3) / 4;
    // layer 1 gemm: x*W1*dinv -> hs
    k_gemm<256, false><<<gRows, TPB, 0, stream>>>(x, W1, dinv, hs, n);
    // agg1 + fused gemm2: hs -> (agg,relu,+b1) -> *W2*dinv -> hb
    k_agg<true><<<gNode, TPB, 0, stream>>>(hs, csr_off, csr_src, dinv, b1, W2, hb, n);
    // agg2: hb -> (agg,relu,+b2) -> hs
    k_agg<false><<<gNode, TPB, 0, stream>>>(hb, csr_off, csr_src, dinv, b2, nullptr, hs, n);

    int nwaves16 = (n + 15) / 16;
    k_pool<<<(nwaves16 + 3) / 4, TPB, 0, stream>>>(hs, batch, n, gsum, gcnt);
    k_head1<<<32, TPB, 0, stream>>>(gsum, gcnt, fc1w, fc1b, zbuf);
    k_head2<<<1, TPB, 0, stream>>>(zbuf, fc2w, fc2b, (float*)d_out);
}

// Round 6
// 253.939 us; speedup vs baseline: 1.0311x; 1.0311x over previous
//
#include <hip/hip_runtime.h>

// GNN: 2x GCNConv(relu) + mean-pool + MLP head.
// Sizes fixed: N=50000, E=800000, F_IN=256, H=64, NG=64, NC=4.
//
// R9: hs/hb bf16, f32 accumulate. R11: dual-edge packed gather.
// R13: GEMMs on bf16 MFMA (16x16x32), split-bf16 hi/lo, swizzled LDS.
// R15: poolhead last-block fusion REGRESSED (threadfence stall) -> reverted.
// R16: gemm2 fused into agg1 (free under gather latency) -> kept.
// R17: shfl-distributed gather REGRESSED (42.4 -> 49us): ds_bpermute added
//      an LDS-pipe stage to the dependency chain (VALUBusy 33->52%).
// R18 (this round): R17 minus shfl. Per 32-edge batch: 16 clamped
//      BROADCAST csr_src loads (R11's proven pattern, back-to-back) ->
//      all <=16 dual-edge gathers issued in one predicated batch
//      (invalid slots clamp to own hot row) -> predicated adds.
//      2 dependent latency rounds per node; no 8/4/2/1 tail chains.

#define TPB 256
#define CHUNK_A 4096
#define BCAP 4608          // per-bucket staging capacity (mean 4096, +8 sigma)

typedef unsigned short bfu;
typedef __attribute__((ext_vector_type(8))) short s16x8;
typedef __attribute__((ext_vector_type(4))) float f32x4;

__device__ __forceinline__ float bf2f(bfu u) {
    union { unsigned u32; float f; } c; c.u32 = ((unsigned)u) << 16; return c.f;
}
__device__ __forceinline__ bfu f2bf(float f) {
    union { float f; unsigned u; } c; c.f = f;
    unsigned r = 0x7FFFu + ((c.u >> 16) & 1u);     // round-to-nearest-even
    return (bfu)((c.u + r) >> 16);
}
__device__ __forceinline__ float blo(unsigned w) {
    union { unsigned u32; float f; } c; c.u32 = w << 16; return c.f;
}
__device__ __forceinline__ float bhi(unsigned w) {
    union { unsigned u32; float f; } c; c.u32 = w & 0xFFFF0000u; return c.f;
}
__device__ __forceinline__ void split_bf(float x, bfu& h, bfu& l) {
    h = f2bf(x);
    l = f2bf(x - bf2f(h));
}

// ---------------- pass A: chunked bucket staging ----------------
// packed edge: (src<<8) | (dst & 255); requires n <= 65536, nbuck <= 256.

__global__ __launch_bounds__(TPB) void k_passA(const int* __restrict__ srcv,
                                               const int* __restrict__ dstv, int E,
                                               int* __restrict__ gcur,
                                               int* __restrict__ staged, int nbuck) {
    __shared__ int pk[CHUNK_A];
    __shared__ int hist[256];
    __shared__ int ebase[256];
    __shared__ int gbase[256];
    __shared__ int lcur[256];
    int t = threadIdx.x;
    int e0 = blockIdx.x * CHUNK_A;
    int e1 = e0 + CHUNK_A; if (e1 > E) e1 = E;

    hist[t] = 0; lcur[t] = 0;
    __syncthreads();
    for (int i = e0 + t; i < e1; i += TPB) atomicAdd(&hist[dstv[i] >> 8], 1);
    __syncthreads();
    int v = hist[t];
    ebase[t] = v;
    __syncthreads();
    for (int off = 1; off < 256; off <<= 1) {
        int u = (t >= off) ? ebase[t - off] : 0;
        __syncthreads();
        ebase[t] += u;
        __syncthreads();
    }
    ebase[t] -= v;
    if (t < nbuck && v > 0) gbase[t] = t * BCAP + atomicAdd(&gcur[t], v);
    __syncthreads();
    for (int i = e0 + t; i < e1; i += TPB) {
        int d = dstv[i];
        int s = srcv[i];
        int b = d >> 8;
        int r = atomicAdd(&lcur[b], 1);
        pk[ebase[b] + r] = (s << 8) | (d & 255);
    }
    __syncthreads();
    int wave = t >> 6, lane = t & 63;
    for (int b = wave; b < nbuck; b += 4) {
        int c = hist[b];
        int lb = ebase[b];
        int gb = gbase[b];
        for (int j = lane; j < c; j += 64) staged[gb + j] = pk[lb + j];
    }
}

// ---------------- pass B: per-bucket node sort + csr_off + dinv ----------------

__global__ __launch_bounds__(TPB) void k_passB(const int* __restrict__ staged,
                                               const int* __restrict__ gcur,
                                               int* __restrict__ csr_off,
                                               int* __restrict__ csr_src,
                                               float* __restrict__ dinv,
                                               int n, int nbuck) {
    __shared__ int pk[BCAP];
    __shared__ int soff[256];
    __shared__ int hist[256];
    __shared__ int nbase[256];
    __shared__ int cur[256];
    int b = blockIdx.x;
    int n0 = b << 8;
    int n1 = n0 + 256; if (n1 > n) n1 = n;
    int cnt = gcur[b];
    int t = threadIdx.x;

    int cv = (t < nbuck) ? gcur[t] : 0;
    soff[t] = cv;
    hist[t] = 0; cur[t] = 0;
    __syncthreads();
    for (int off = 1; off < 256; off <<= 1) {
        int u = (t >= off) ? soff[t - off] : 0;
        __syncthreads();
        soff[t] += u;
        __syncthreads();
    }
    int base = soff[b] - cnt;   // exclusive prefix at bucket b

    for (int i = t; i < cnt; i += TPB) pk[i] = staged[b * BCAP + i];
    __syncthreads();
    for (int i = t; i < cnt; i += TPB) atomicAdd(&hist[pk[i] & 255], 1);
    __syncthreads();
    int v = hist[t];
    nbase[t] = v;
    __syncthreads();
    for (int off = 1; off < 256; off <<= 1) {
        int u = (t >= off) ? nbase[t - off] : 0;
        __syncthreads();
        nbase[t] += u;
        __syncthreads();
    }
    nbase[t] -= v;
    if (n0 + t < n1) {
        csr_off[n0 + t] = base + nbase[t];
        dinv[n0 + t] = rsqrtf((float)(v + 1));   // +1 self loop
    }
    if (b == nbuck - 1 && t == 0) csr_off[n] = base + cnt;
    __syncthreads();
    for (int i = t; i < cnt; i += TPB) {
        int p = pk[i];
        int dloc = p & 255;
        int r = atomicAdd(&cur[dloc], 1);
        csr_src[base + nbase[dloc] + r] = p >> 8;
    }
}

// ---------------- GEMM (MFMA): C[r][j] = dinv[r] * sum_k A[r][k] * W[k][j] ----------------
// Block = 128 rows x 64 cols, 4 waves; wave = 32 rows x 64 cols
// (2 row-tiles x 4 col-tiles of 16x16, K-step 32). K-chunk 64 in LDS.
// f32 A: split-bf16 hi/lo planes, products hi*hi + hi*lo + lo*hi.
// LDS XOR swizzle: element k ^ ((rc&7)<<3), 16B-granule permutation.
// C/D map (m89-verified): col=lane&15, row=(lane>>4)*4+reg.

__device__ __forceinline__ int swz(int rc, int k) {
    return rc * 64 + (k ^ ((rc & 7) << 3));
}

template <int K, bool BF16A>
__global__ __launch_bounds__(TPB) void k_gemm(const void* __restrict__ Av,
                                              const float* __restrict__ W,
                                              const float* __restrict__ dinv,
                                              bfu* __restrict__ C, int n) {
    __shared__ __align__(16) ushort Ah[128 * 64];
    __shared__ __align__(16) ushort Al[BF16A ? 64 : 128 * 64];
    __shared__ __align__(16) ushort Bh[64 * 64];
    __shared__ __align__(16) ushort Bl[64 * 64];

    const int t = threadIdx.x;
    const int wave = t >> 6, lane = t & 63;
    const int rbase = blockIdx.x * 128;

    f32x4 acc[2][4];
#pragma unroll
    for (int i = 0; i < 2; i++)
#pragma unroll
        for (int j = 0; j < 4; j++) acc[i][j] = {0.f, 0.f, 0.f, 0.f};

    for (int kc = 0; kc < K; kc += 64) {
        // ---- stage B: W chunk [64k x 64c] -> transposed bf16 hi/lo ----
        {
            int c = t & 63;
            int kg = (t >> 6) << 4;   // 16 k's per wave
#pragma unroll
            for (int q = 0; q < 4; q++) {
                ushort4 h4, l4;
#pragma unroll
                for (int j = 0; j < 4; j++) {
                    float w = W[(size_t)(kc + kg + q * 4 + j) * 64 + c];
                    bfu hh, ll; split_bf(w, hh, ll);
                    ((bfu*)&h4)[j] = hh;
                    ((bfu*)&l4)[j] = ll;
                }
                *(ushort4*)&Bh[swz(c, kg + q * 4)] = h4;
                *(ushort4*)&Bl[swz(c, kg + q * 4)] = l4;
            }
        }
        // ---- stage A chunk [128r x 64k] ----
        if (!BF16A) {
            const float* A = (const float*)Av;
#pragma unroll
            for (int q = 0; q < 8; q++) {
                int idx = q * 256 + t;
                int row = idx >> 4;
                int k4 = (idx & 15) << 2;
                int r = rbase + row;
                float4 xv = make_float4(0.f, 0.f, 0.f, 0.f);
                if (r < n) xv = *(const float4*)&A[(size_t)r * K + kc + k4];
                ushort4 h4, l4;
                split_bf(xv.x, ((bfu*)&h4)[0], ((bfu*)&l4)[0]);
                split_bf(xv.y, ((bfu*)&h4)[1], ((bfu*)&l4)[1]);
                split_bf(xv.z, ((bfu*)&h4)[2], ((bfu*)&l4)[2]);
                split_bf(xv.w, ((bfu*)&h4)[3], ((bfu*)&l4)[3]);
                *(ushort4*)&Ah[swz(row, k4)] = h4;
                *(ushort4*)&Al[swz(row, k4)] = l4;
            }
        } else {
            const bfu* A = (const bfu*)Av;
#pragma unroll
            for (int q = 0; q < 4; q++) {
                int idx = q * 256 + t;
                int row = idx >> 3;
                int k8 = (idx & 7) << 3;
                int r = rbase + row;
                uint4 v = make_uint4(0u, 0u, 0u, 0u);
                if (r < n) v = *(const uint4*)(A + (size_t)r * 64 + k8);
                *(uint2*)&Ah[swz(row, k8)]     = make_uint2(v.x, v.y);
                *(uint2*)&Ah[swz(row, k8 + 4)] = make_uint2(v.z, v.w);
            }
        }
        __syncthreads();

        // ---- MFMA compute ----
        const int rl = lane & 15;            // M/N index within tile
        const int kg8 = (lane >> 4) << 3;    // k offset of this lane group
#pragma unroll
        for (int ks = 0; ks < 2; ks++) {
            int k0 = ks * 32 + kg8;
            s16x8 a_h[2], a_l[2], b_h[4], b_l[4];
#pragma unroll
            for (int rt = 0; rt < 2; rt++) {
                int row = wave * 32 + rt * 16 + rl;
                a_h[rt] = *(const s16x8*)&Ah[swz(row, k0)];
                if (!BF16A) a_l[rt] = *(const s16x8*)&Al[swz(row, k0)];
            }
#pragma unroll
            for (int ct = 0; ct < 4; ct++) {
                int cc = ct * 16 + rl;
                b_h[ct] = *(const s16x8*)&Bh[swz(cc, k0)];
                b_l[ct] = *(const s16x8*)&Bl[swz(cc, k0)];
            }
#pragma unroll
            for (int rt = 0; rt < 2; rt++)
#pragma unroll
                for (int ct = 0; ct < 4; ct++) {
                    acc[rt][ct] = __builtin_amdgcn_mfma_f32_16x16x32_bf16(
                        a_h[rt], b_h[ct], acc[rt][ct], 0, 0, 0);
                    acc[rt][ct] = __builtin_amdgcn_mfma_f32_16x16x32_bf16(
                        a_h[rt], b_l[ct], acc[rt][ct], 0, 0, 0);
                    if (!BF16A)
                        acc[rt][ct] = __builtin_amdgcn_mfma_f32_16x16x32_bf16(
                            a_l[rt], b_h[ct], acc[rt][ct], 0, 0, 0);
                }
        }
        __syncthreads();
    }

    // ---- epilogue ----
    const int rl = lane & 15;
    const int rq = (lane >> 4) << 2;
#pragma unroll
    for (int rt = 0; rt < 2; rt++) {
#pragma unroll
        for (int reg = 0; reg < 4; reg++) {
            int r = rbase + wave * 32 + rt * 16 + rq + reg;
            if (r < n) {
                float d = dinv[r];
#pragma unroll
                for (int ct = 0; ct < 4; ct++) {
                    C[(size_t)r * 64 + ct * 16 + rl] = f2bf(acc[rt][ct][reg] * d);
                }
            }
        }
    }
}

// ---------------- Aggregation (R18): flat-batch predicated gather ----------------
// Wave = 1 node; 2 halves of 32 lanes; lane handles 2 features (unsigned).
// Per 32-edge batch: 16 clamped BROADCAST csr_src loads (independent,
// back-to-back; R11's proven pattern, no shfl/LDS stage) -> all <=16
// dual-edge gathers issued in one predicated batch (invalid slots clamp
// to own hot row) -> predicated adds. Uniform rem>16 branch skips the
// second gather group for deg<=16 (~53% of nodes). 2 dependent latency
// rounds per node; no serialized 8/4/2/1 tails.
// FUSE: per-wave 64x64 W2 matmul on the relu'd row (gemm2 fusion, R16).

template <bool FUSE>
__global__ __launch_bounds__(TPB) void k_agg(const bfu* __restrict__ hs,
                                             const int* __restrict__ csr_off,
                                             const int* __restrict__ csr_src,
                                             const float* __restrict__ dinv,
                                             const float* __restrict__ bias,
                                             const float* __restrict__ W2,
                                             bfu* __restrict__ out, int n) {
    __shared__ float rowbuf[4][64];
    int wv = threadIdx.x >> 6;
    int node = blockIdx.x * 4 + wv;
    int lane = threadIdx.x & 63;
    int half = lane >> 5;          // 0 or 1
    int fl = (lane & 31) * 2;      // feature pair base
    if (node >= n) return;
    int p0 = csr_off[node];
    int p1 = csr_off[node + 1];
    int deg = p1 - p0;
    float d = dinv[node];          // issue early, needed late

    // self-loop row (independent, issued before index loads)
    unsigned gself = *(const unsigned*)(hs + (size_t)node * 64 + fl);

    float ax = 0.f, ay = 0.f;
    for (int base = 0; base < deg; base += 32) {   // 1 iteration for deg<=32 (99.99%)
        int rem = deg - base;
        int pb = p0 + base;
        int idx[16];
        unsigned gb[16];
        // round 1: clamped broadcast index loads (all independent)
#pragma unroll
        for (int i = 0; i < 8; i++) {
            int li = pb + 2 * i + half;
            idx[i] = csr_src[li < p1 ? li : pb];
        }
        if (rem > 16) {
#pragma unroll
            for (int i = 8; i < 16; i++) {
                int li = pb + 2 * i + half;
                idx[i] = csr_src[li < p1 ? li : pb];
            }
        }
        // round 2: all gathers issued back-to-back, clamped to own row
#pragma unroll
        for (int i = 0; i < 8; i++) {
            int e = 2 * i + half;
            gb[i] = *(const unsigned*)(hs + (size_t)(e < rem ? idx[i] : node) * 64 + fl);
        }
        if (rem > 16) {
#pragma unroll
            for (int i = 8; i < 16; i++) {
                int e = 2 * i + half;
                gb[i] = *(const unsigned*)(hs + (size_t)(e < rem ? idx[i] : node) * 64 + fl);
            }
        }
        // predicated adds
#pragma unroll
        for (int i = 0; i < 8; i++) {
            int e = 2 * i + half;
            unsigned g = gb[i];
            ax += (e < rem) ? blo(g) : 0.f;
            ay += (e < rem) ? bhi(g) : 0.f;
        }
        if (rem > 16) {
#pragma unroll
            for (int i = 8; i < 16; i++) {
                int e = 2 * i + half;
                unsigned g = gb[i];
                ax += (e < rem) ? blo(g) : 0.f;
                ay += (e < rem) ? bhi(g) : 0.f;
            }
        }
    }
    if (half == 0) { ax += blo(gself); ay += bhi(gself); }

    // combine halves (same fl in lane and lane^32)
    ax += __shfl_xor(ax, 32);
    ay += __shfl_xor(ay, 32);

    float vx = fmaxf(d * ax + bias[fl + 0], 0.f);
    float vy = fmaxf(d * ay + bias[fl + 1], 0.f);
    if (!FUSE) {
        if (half == 0) {
            ushort2 o;
            o.x = f2bf(vx);
            o.y = f2bf(vy);
            *(ushort2*)(out + (size_t)node * 64 + fl) = o;
        }
    } else {
        // fused gemm2: out[node][lane] = f2bf(d * sum_k row[k] * W2[k][lane])
        if (half == 0) { rowbuf[wv][fl] = vx; rowbuf[wv][fl + 1] = vy; }
        __builtin_amdgcn_wave_barrier();   // ds_write before ds_read (same wave: HW in-order)
        float a = 0.f;
#pragma unroll 16
        for (int k = 0; k < 64; k++) a += rowbuf[wv][k] * W2[k * 64 + lane];
        out[(size_t)node * 64 + lane] = f2bf(d * a);
    }
}

// ---------------- Pool: sorted batch; uniform-chunk fast path (bf16 reads) ----------------

__global__ __launch_bounds__(TPB) void k_pool(const bfu* __restrict__ h,
                                              const int* __restrict__ batch, int n,
                                              float* __restrict__ gsum,
                                              int* __restrict__ gcnt) {
    const int CH = 16;
    int wid = blockIdx.x * 4 + (threadIdx.x >> 6);
    int lane = threadIdx.x & 63;
    int i0 = wid * CH;
    if (i0 >= n) return;
    int i1 = i0 + CH; if (i1 > n) i1 = n;
    int g0 = batch[i0];
    int g1 = batch[i1 - 1];
    if (g0 == g1) {
        float acc = 0.f;
#pragma unroll
        for (int i = 0; i < CH; i++) {
            int idx = i0 + i;
            if (idx < i1) acc += bf2f(h[(size_t)idx * 64 + lane]);
        }
        atomicAdd(&gsum[g0 * 64 + lane], acc);
        if (lane == 0) atomicAdd(&gcnt[g0], i1 - i0);
    } else {
        int cur = g0;
        float acc = 0.f;
        int cnt = 0;
        for (int i = i0; i < i1; i++) {
            int g = batch[i];
            if (g != cur) {
                atomicAdd(&gsum[cur * 64 + lane], acc);
                if (lane == 0) atomicAdd(&gcnt[cur], cnt);
                acc = 0.f; cnt = 0; cur = g;
            }
            acc += bf2f(h[(size_t)i * 64 + lane]);
            cnt++;
        }
        atomicAdd(&gsum[cur * 64 + lane], acc);
        if (lane == 0) atomicAdd(&gcnt[cur], cnt);
    }
}

// ---------------- Head, stage 1 ----------------

__global__ __launch_bounds__(TPB) void k_head1(const float* __restrict__ gsum,
                                               const int* __restrict__ gcnt,
                                               const float* __restrict__ fc1w,
                                               const float* __restrict__ fc1b,
                                               float* __restrict__ z) {
    int t = threadIdx.x;
    int g = blockIdx.x * 2 + (t >> 7);
    int o = t & 127;
    int c = gcnt[g]; if (c < 1) c = 1;
    float inv = 1.0f / (float)c;
    float a = fc1b[o];
#pragma unroll 16
    for (int j = 0; j < 64; j++) {
        float pj = gsum[g * 64 + j] * inv;
        a += pj * fc1w[j * 128 + o];
    }
    z[g * 128 + o] = fmaxf(a, 0.f);
}

// ---------------- Head, stage 2 ----------------

__global__ __launch_bounds__(TPB) void k_head2(const float* __restrict__ z,
                                               const float* __restrict__ fc2w,
                                               const float* __restrict__ fc2b,
                                               float* __restrict__ out) {
    int t = threadIdx.x;
    int g = t >> 2, c = t & 3;
    float a = fc2b[c];
#pragma unroll 16
    for (int o = 0; o < 128; o++) a += z[g * 128 + o] * fc2w[o * 4 + c];
    out[t] = a;
}

// ---------------- launch ----------------

extern "C" void kernel_launch(void* const* d_in, const int* in_sizes, int n_in,
                              void* d_out, int out_size, void* d_ws, size_t ws_size,
                              hipStream_t stream) {
    const float* x    = (const float*)d_in[0];
    const int*   ei   = (const int*)d_in[1];
    const int*   batch= (const int*)d_in[2];
    const float* W1   = (const float*)d_in[3];
    const float* b1   = (const float*)d_in[4];
    const float* W2   = (const float*)d_in[5];
    const float* b2   = (const float*)d_in[6];
    const float* fc1w = (const float*)d_in[7];
    const float* fc1b = (const float*)d_in[8];
    const float* fc2w = (const float*)d_in[9];
    const float* fc2b = (const float*)d_in[10];

    const int n = in_sizes[2];        // 50000
    const int E = in_sizes[1] / 2;    // 800000
    const int* srcv = ei;
    const int* dstv = ei + E;
    const int nbuck = (n + 255) >> 8; // 196 (must be <= 256)

    // workspace carve; zeroed region contiguous at front
    char* w = (char*)d_ws;
    int*   gcur   = (int*)w;            w += 256 * 4;
    int*   gcnt   = (int*)w;            w += 64 * 4;
    float* gsum   = (float*)w;          w += 64 * 64 * 4;
    size_t zbytes = (size_t)w - (size_t)d_ws;
    int*   csr_off= (int*)w;            w += (size_t)(n + 1) * 4;
    float* dinv   = (float*)w;          w += (size_t)n * 4;
    int*   csr_src= (int*)w;            w += (size_t)E * 4;
    int*   staged = (int*)w;            w += (size_t)nbuck * BCAP * 4;
    float* zbuf   = (float*)w;          w += 64 * 128 * 4;
    w = (char*)(((size_t)w + 255) & ~(size_t)255);
    bfu* hs = (bfu*)w;                  w += (size_t)n * 64 * 2;
    w = (char*)(((size_t)w + 255) & ~(size_t)255);
    bfu* hb = (bfu*)w;                  w += (size_t)n * 64 * 2;

    hipMemsetAsync(d_ws, 0, zbytes, stream);

    int gA = (E + CHUNK_A - 1) / CHUNK_A;   // 196
    k_passA<<<gA, TPB, 0, stream>>>(srcv, dstv, E, gcur, staged, nbuck);
    k_passB<<<nbuck, TPB, 0, stream>>>(staged, gcur, csr_off, csr_src, dinv, n, nbuck);

    int gRows = (n + 127) / 128;
    int gNode = (n + 3) / 4;
    // layer 1 gemm: x*W1*dinv -> hs
    k_gemm<256, false><<<gRows, TPB, 0, stream>>>(x, W1, dinv, hs, n);
    // agg1 + fused gemm2: hs -> (agg,relu,+b1) -> *W2*dinv -> hb
    k_agg<true><<<gNode, TPB, 0, stream>>>(hs, csr_off, csr_src, dinv, b1, W2, hb, n);
    // agg2: hb -> (agg,relu,+b2) -> hs
    k_agg<false><<<gNode, TPB, 0, stream>>>(hb, csr_off, csr_src, dinv, b2, nullptr, hs, n);

    int nwaves16 = (n + 15) / 16;
    k_pool<<<(nwaves16 + 3) / 4, TPB, 0, stream>>>(hs, batch, n, gsum, gcnt);
    k_head1<<<32, TPB, 0, stream>>>(gsum, gcnt, fc1w, fc1b, zbuf);
    k_head2<<<1, TPB, 0, stream>>>(zbuf, fc2w, fc2b, (float*)d_out);
}

// Round 7
// 252.356 us; speedup vs baseline: 1.0376x; 1.0063x over previous
//
#include <hip/hip_runtime.h>

// GNN: 2x GCNConv(relu) + mean-pool + MLP head.
// Sizes fixed: N=50000, E=800000, F_IN=256, H=64, NG=64, NC=4.
//
// R9: hs/hb bf16, f32 accumulate. R11: dual-edge packed gather.
// R13: GEMMs on bf16 MFMA (16x16x32), split-bf16 hi/lo, swizzled LDS.
// R15: poolhead last-block fusion REGRESSED (threadfence stall) -> reverted.
// R16: gemm2 fused into agg1 (free under gather latency) -> kept.
// R17: shfl-distributed gather REGRESSED (ds_bpermute in dep chain).
// R18: flat-batch predicated dword gather: 45.4us (VALU 58%) — stall time
//      unchanged across R11/R17/R18 -> NOT latency-bound; bound by
//      per-request address work (4B/lane) + predication VALU.
// R19 (this round): WIDE gather. Lane map g=lane>>3 (row slot), c=lane&7
//      (8-feat chunk): one dwordx4 gather = 8 rows x 128B (16B/lane, 4x
//      bytes/address). Index load = csr_src[p0+base+g], broadcast in
//      8-lane groups, no shfl. Feature sums via 3 shfl_xor rounds ONCE
//      per node. Per-row VALU ~-40%, gather instrs ~/4.

#define TPB 256
#define CHUNK_A 4096
#define BCAP 4608          // per-bucket staging capacity (mean 4096, +8 sigma)

typedef unsigned short bfu;
typedef __attribute__((ext_vector_type(8))) short s16x8;
typedef __attribute__((ext_vector_type(4))) float f32x4;

__device__ __forceinline__ float bf2f(bfu u) {
    union { unsigned u32; float f; } c; c.u32 = ((unsigned)u) << 16; return c.f;
}
__device__ __forceinline__ bfu f2bf(float f) {
    union { float f; unsigned u; } c; c.f = f;
    unsigned r = 0x7FFFu + ((c.u >> 16) & 1u);     // round-to-nearest-even
    return (bfu)((c.u + r) >> 16);
}
__device__ __forceinline__ float blo(unsigned w) {
    union { unsigned u32; float f; } c; c.u32 = w << 16; return c.f;
}
__device__ __forceinline__ float bhi(unsigned w) {
    union { unsigned u32; float f; } c; c.u32 = w & 0xFFFF0000u; return c.f;
}
__device__ __forceinline__ void split_bf(float x, bfu& h, bfu& l) {
    h = f2bf(x);
    l = f2bf(x - bf2f(h));
}

// ---------------- pass A: chunked bucket staging ----------------
// packed edge: (src<<8) | (dst & 255); requires n <= 65536, nbuck <= 256.

__global__ __launch_bounds__(TPB) void k_passA(const int* __restrict__ srcv,
                                               const int* __restrict__ dstv, int E,
                                               int* __restrict__ gcur,
                                               int* __restrict__ staged, int nbuck) {
    __shared__ int pk[CHUNK_A];
    __shared__ int hist[256];
    __shared__ int ebase[256];
    __shared__ int gbase[256];
    __shared__ int lcur[256];
    int t = threadIdx.x;
    int e0 = blockIdx.x * CHUNK_A;
    int e1 = e0 + CHUNK_A; if (e1 > E) e1 = E;

    hist[t] = 0; lcur[t] = 0;
    __syncthreads();
    for (int i = e0 + t; i < e1; i += TPB) atomicAdd(&hist[dstv[i] >> 8], 1);
    __syncthreads();
    int v = hist[t];
    ebase[t] = v;
    __syncthreads();
    for (int off = 1; off < 256; off <<= 1) {
        int u = (t >= off) ? ebase[t - off] : 0;
        __syncthreads();
        ebase[t] += u;
        __syncthreads();
    }
    ebase[t] -= v;
    if (t < nbuck && v > 0) gbase[t] = t * BCAP + atomicAdd(&gcur[t], v);
    __syncthreads();
    for (int i = e0 + t; i < e1; i += TPB) {
        int d = dstv[i];
        int s = srcv[i];
        int b = d >> 8;
        int r = atomicAdd(&lcur[b], 1);
        pk[ebase[b] + r] = (s << 8) | (d & 255);
    }
    __syncthreads();
    int wave = t >> 6, lane = t & 63;
    for (int b = wave; b < nbuck; b += 4) {
        int c = hist[b];
        int lb = ebase[b];
        int gb = gbase[b];
        for (int j = lane; j < c; j += 64) staged[gb + j] = pk[lb + j];
    }
}

// ---------------- pass B: per-bucket node sort + csr_off + dinv ----------------

__global__ __launch_bounds__(TPB) void k_passB(const int* __restrict__ staged,
                                               const int* __restrict__ gcur,
                                               int* __restrict__ csr_off,
                                               int* __restrict__ csr_src,
                                               float* __restrict__ dinv,
                                               int n, int nbuck) {
    __shared__ int pk[BCAP];
    __shared__ int soff[256];
    __shared__ int hist[256];
    __shared__ int nbase[256];
    __shared__ int cur[256];
    int b = blockIdx.x;
    int n0 = b << 8;
    int n1 = n0 + 256; if (n1 > n) n1 = n;
    int cnt = gcur[b];
    int t = threadIdx.x;

    int cv = (t < nbuck) ? gcur[t] : 0;
    soff[t] = cv;
    hist[t] = 0; cur[t] = 0;
    __syncthreads();
    for (int off = 1; off < 256; off <<= 1) {
        int u = (t >= off) ? soff[t - off] : 0;
        __syncthreads();
        soff[t] += u;
        __syncthreads();
    }
    int base = soff[b] - cnt;   // exclusive prefix at bucket b

    for (int i = t; i < cnt; i += TPB) pk[i] = staged[b * BCAP + i];
    __syncthreads();
    for (int i = t; i < cnt; i += TPB) atomicAdd(&hist[pk[i] & 255], 1);
    __syncthreads();
    int v = hist[t];
    nbase[t] = v;
    __syncthreads();
    for (int off = 1; off < 256; off <<= 1) {
        int u = (t >= off) ? nbase[t - off] : 0;
        __syncthreads();
        nbase[t] += u;
        __syncthreads();
    }
    nbase[t] -= v;
    if (n0 + t < n1) {
        csr_off[n0 + t] = base + nbase[t];
        dinv[n0 + t] = rsqrtf((float)(v + 1));   // +1 self loop
    }
    if (b == nbuck - 1 && t == 0) csr_off[n] = base + cnt;
    __syncthreads();
    for (int i = t; i < cnt; i += TPB) {
        int p = pk[i];
        int dloc = p & 255;
        int r = atomicAdd(&cur[dloc], 1);
        csr_src[base + nbase[dloc] + r] = p >> 8;
    }
}

// ---------------- GEMM (MFMA): C[r][j] = dinv[r] * sum_k A[r][k] * W[k][j] ----------------
// Block = 128 rows x 64 cols, 4 waves; wave = 32 rows x 64 cols
// (2 row-tiles x 4 col-tiles of 16x16, K-step 32). K-chunk 64 in LDS.
// f32 A: split-bf16 hi/lo planes, products hi*hi + hi*lo + lo*hi.
// LDS XOR swizzle: element k ^ ((rc&7)<<3), 16B-granule permutation.
// C/D map (m89-verified): col=lane&15, row=(lane>>4)*4+reg.

__device__ __forceinline__ int swz(int rc, int k) {
    return rc * 64 + (k ^ ((rc & 7) << 3));
}

template <int K, bool BF16A>
__global__ __launch_bounds__(TPB) void k_gemm(const void* __restrict__ Av,
                                              const float* __restrict__ W,
                                              const float* __restrict__ dinv,
                                              bfu* __restrict__ C, int n) {
    __shared__ __align__(16) ushort Ah[128 * 64];
    __shared__ __align__(16) ushort Al[BF16A ? 64 : 128 * 64];
    __shared__ __align__(16) ushort Bh[64 * 64];
    __shared__ __align__(16) ushort Bl[64 * 64];

    const int t = threadIdx.x;
    const int wave = t >> 6, lane = t & 63;
    const int rbase = blockIdx.x * 128;

    f32x4 acc[2][4];
#pragma unroll
    for (int i = 0; i < 2; i++)
#pragma unroll
        for (int j = 0; j < 4; j++) acc[i][j] = {0.f, 0.f, 0.f, 0.f};

    for (int kc = 0; kc < K; kc += 64) {
        // ---- stage B: W chunk [64k x 64c] -> transposed bf16 hi/lo ----
        {
            int c = t & 63;
            int kg = (t >> 6) << 4;   // 16 k's per wave
#pragma unroll
            for (int q = 0; q < 4; q++) {
                ushort4 h4, l4;
#pragma unroll
                for (int j = 0; j < 4; j++) {
                    float w = W[(size_t)(kc + kg + q * 4 + j) * 64 + c];
                    bfu hh, ll; split_bf(w, hh, ll);
                    ((bfu*)&h4)[j] = hh;
                    ((bfu*)&l4)[j] = ll;
                }
                *(ushort4*)&Bh[swz(c, kg + q * 4)] = h4;
                *(ushort4*)&Bl[swz(c, kg + q * 4)] = l4;
            }
        }
        // ---- stage A chunk [128r x 64k] ----
        if (!BF16A) {
            const float* A = (const float*)Av;
#pragma unroll
            for (int q = 0; q < 8; q++) {
                int idx = q * 256 + t;
                int row = idx >> 4;
                int k4 = (idx & 15) << 2;
                int r = rbase + row;
                float4 xv = make_float4(0.f, 0.f, 0.f, 0.f);
                if (r < n) xv = *(const float4*)&A[(size_t)r * K + kc + k4];
                ushort4 h4, l4;
                split_bf(xv.x, ((bfu*)&h4)[0], ((bfu*)&l4)[0]);
                split_bf(xv.y, ((bfu*)&h4)[1], ((bfu*)&l4)[1]);
                split_bf(xv.z, ((bfu*)&h4)[2], ((bfu*)&l4)[2]);
                split_bf(xv.w, ((bfu*)&h4)[3], ((bfu*)&l4)[3]);
                *(ushort4*)&Ah[swz(row, k4)] = h4;
                *(ushort4*)&Al[swz(row, k4)] = l4;
            }
        } else {
            const bfu* A = (const bfu*)Av;
#pragma unroll
            for (int q = 0; q < 4; q++) {
                int idx = q * 256 + t;
                int row = idx >> 3;
                int k8 = (idx & 7) << 3;
                int r = rbase + row;
                uint4 v = make_uint4(0u, 0u, 0u, 0u);
                if (r < n) v = *(const uint4*)(A + (size_t)r * 64 + k8);
                *(uint2*)&Ah[swz(row, k8)]     = make_uint2(v.x, v.y);
                *(uint2*)&Ah[swz(row, k8 + 4)] = make_uint2(v.z, v.w);
            }
        }
        __syncthreads();

        // ---- MFMA compute ----
        const int rl = lane & 15;            // M/N index within tile
        const int kg8 = (lane >> 4) << 3;    // k offset of this lane group
#pragma unroll
        for (int ks = 0; ks < 2; ks++) {
            int k0 = ks * 32 + kg8;
            s16x8 a_h[2], a_l[2], b_h[4], b_l[4];
#pragma unroll
            for (int rt = 0; rt < 2; rt++) {
                int row = wave * 32 + rt * 16 + rl;
                a_h[rt] = *(const s16x8*)&Ah[swz(row, k0)];
                if (!BF16A) a_l[rt] = *(const s16x8*)&Al[swz(row, k0)];
            }
#pragma unroll
            for (int ct = 0; ct < 4; ct++) {
                int cc = ct * 16 + rl;
                b_h[ct] = *(const s16x8*)&Bh[swz(cc, k0)];
                b_l[ct] = *(const s16x8*)&Bl[swz(cc, k0)];
            }
#pragma unroll
            for (int rt = 0; rt < 2; rt++)
#pragma unroll
                for (int ct = 0; ct < 4; ct++) {
                    acc[rt][ct] = __builtin_amdgcn_mfma_f32_16x16x32_bf16(
                        a_h[rt], b_h[ct], acc[rt][ct], 0, 0, 0);
                    acc[rt][ct] = __builtin_amdgcn_mfma_f32_16x16x32_bf16(
                        a_h[rt], b_l[ct], acc[rt][ct], 0, 0, 0);
                    if (!BF16A)
                        acc[rt][ct] = __builtin_amdgcn_mfma_f32_16x16x32_bf16(
                            a_l[rt], b_h[ct], acc[rt][ct], 0, 0, 0);
                }
        }
        __syncthreads();
    }

    // ---- epilogue ----
    const int rl = lane & 15;
    const int rq = (lane >> 4) << 2;
#pragma unroll
    for (int rt = 0; rt < 2; rt++) {
#pragma unroll
        for (int reg = 0; reg < 4; reg++) {
            int r = rbase + wave * 32 + rt * 16 + rq + reg;
            if (r < n) {
                float d = dinv[r];
#pragma unroll
                for (int ct = 0; ct < 4; ct++) {
                    C[(size_t)r * 64 + ct * 16 + rl] = f2bf(acc[rt][ct][reg] * d);
                }
            }
        }
    }
}

// ---------------- Aggregation (R19): wide row gather (dwordx4) ----------------
// Wave = 1 node. Lane map: g = lane>>3 (row slot 0..7), c = lane&7
// (8-feature chunk). One dwordx4 gather = 8 neighbor rows x 128B
// (16B/lane). Index load csr_src[p0+base+g]: broadcast in 8-lane groups,
// one cache line per wave, NO shfl. Per 16-row batch: 2 idx loads +
// 2 gathers (first unpredicated when rem>8). Feature totals via 3
// shfl_xor rounds (8/16/32) once per node; self row added post-reduce.
// FUSE: per-wave 64x64 W2 matmul on the relu'd row (gemm2 fusion, R16).

__device__ __forceinline__ void acc_u4(float* acc, uint4 q) {
    acc[0] += blo(q.x); acc[1] += bhi(q.x);
    acc[2] += blo(q.y); acc[3] += bhi(q.y);
    acc[4] += blo(q.z); acc[5] += bhi(q.z);
    acc[6] += blo(q.w); acc[7] += bhi(q.w);
}

template <bool FUSE>
__global__ __launch_bounds__(TPB) void k_agg(const bfu* __restrict__ hs,
                                             const int* __restrict__ csr_off,
                                             const int* __restrict__ csr_src,
                                             const float* __restrict__ dinv,
                                             const float* __restrict__ bias,
                                             const float* __restrict__ W2,
                                             bfu* __restrict__ out, int n) {
    __shared__ float rowbuf[4][64];
    int wv = threadIdx.x >> 6;
    int node = blockIdx.x * 4 + wv;
    int lane = threadIdx.x & 63;
    int g = lane >> 3;             // row slot within batch
    int c = lane & 7;              // feature chunk (feats c*8 .. c*8+7)
    if (node >= n) return;
    int p0 = csr_off[node];
    int p1 = csr_off[node + 1];
    int deg = p1 - p0;
    float d = dinv[node];          // issue early, needed late

    // self row (hot line), added once after the cross-lane reduction
    uint4 selfv = *(const uint4*)(hs + (size_t)node * 64 + c * 8);

    float acc[8];
#pragma unroll
    for (int j = 0; j < 8; j++) acc[j] = 0.f;

    for (int base = 0; base < deg; base += 16) {
        int rem = deg - base;
        int li0 = p0 + base + g;
        if (rem > 8) {
            // slots 0..7 all valid; slots 8..15 predicated
            int li1 = li0 + 8;
            int idx0 = csr_src[li0];
            int idx1 = csr_src[li1 < p1 ? li1 : p0];
            bool v1 = (8 + g) < rem;
            uint4 q0 = *(const uint4*)(hs + (size_t)idx0 * 64 + c * 8);
            uint4 q1 = *(const uint4*)(hs + (size_t)(v1 ? idx1 : node) * 64 + c * 8);
            if (!v1) q1 = make_uint4(0u, 0u, 0u, 0u);
            acc_u4(acc, q0);
            acc_u4(acc, q1);
        } else {
            bool v0 = g < rem;
            int idx0 = csr_src[li0 < p1 ? li0 : p0];
            uint4 q0 = *(const uint4*)(hs + (size_t)(v0 ? idx0 : node) * 64 + c * 8);
            if (!v0) q0 = make_uint4(0u, 0u, 0u, 0u);
            acc_u4(acc, q0);
        }
    }

    // reduce across row-slot groups (lane bits 3,4,5)
#pragma unroll
    for (int j = 0; j < 8; j++) {
        acc[j] += __shfl_xor(acc[j], 8);
        acc[j] += __shfl_xor(acc[j], 16);
        acc[j] += __shfl_xor(acc[j], 32);
    }
    // self loop (each lane keeps a consistent replicated copy)
    acc_u4(acc, selfv);

    float4 b0 = *(const float4*)&bias[c * 8];
    float4 b1 = *(const float4*)&bias[c * 8 + 4];
    float v[8];
    v[0] = fmaxf(d * acc[0] + b0.x, 0.f);
    v[1] = fmaxf(d * acc[1] + b0.y, 0.f);
    v[2] = fmaxf(d * acc[2] + b0.z, 0.f);
    v[3] = fmaxf(d * acc[3] + b0.w, 0.f);
    v[4] = fmaxf(d * acc[4] + b1.x, 0.f);
    v[5] = fmaxf(d * acc[5] + b1.y, 0.f);
    v[6] = fmaxf(d * acc[6] + b1.z, 0.f);
    v[7] = fmaxf(d * acc[7] + b1.w, 0.f);

    if (!FUSE) {
        if (g == 0) {   // lanes 0..7 write the 128B row
            uint4 o;
            o.x = (unsigned)f2bf(v[0]) | ((unsigned)f2bf(v[1]) << 16);
            o.y = (unsigned)f2bf(v[2]) | ((unsigned)f2bf(v[3]) << 16);
            o.z = (unsigned)f2bf(v[4]) | ((unsigned)f2bf(v[5]) << 16);
            o.w = (unsigned)f2bf(v[6]) | ((unsigned)f2bf(v[7]) << 16);
            *(uint4*)(out + (size_t)node * 64 + c * 8) = o;
        }
    } else {
        // fused gemm2: out[node][lane] = f2bf(d * sum_k row[k] * W2[k][lane])
        if (g == 0) {
            *(float4*)&rowbuf[wv][c * 8]     = make_float4(v[0], v[1], v[2], v[3]);
            *(float4*)&rowbuf[wv][c * 8 + 4] = make_float4(v[4], v[5], v[6], v[7]);
        }
        __builtin_amdgcn_wave_barrier();   // ds_write before ds_read (same wave: HW in-order)
        float a = 0.f;
#pragma unroll 16
        for (int k = 0; k < 64; k++) a += rowbuf[wv][k] * W2[k * 64 + lane];
        out[(size_t)node * 64 + lane] = f2bf(d * a);
    }
}

// ---------------- Pool: sorted batch; uniform-chunk fast path (bf16 reads) ----------------

__global__ __launch_bounds__(TPB) void k_pool(const bfu* __restrict__ h,
                                              const int* __restrict__ batch, int n,
                                              float* __restrict__ gsum,
                                              int* __restrict__ gcnt) {
    const int CH = 16;
    int wid = blockIdx.x * 4 + (threadIdx.x >> 6);
    int lane = threadIdx.x & 63;
    int i0 = wid * CH;
    if (i0 >= n) return;
    int i1 = i0 + CH; if (i1 > n) i1 = n;
    int g0 = batch[i0];
    int g1 = batch[i1 - 1];
    if (g0 == g1) {
        float acc = 0.f;
#pragma unroll
        for (int i = 0; i < CH; i++) {
            int idx = i0 + i;
            if (idx < i1) acc += bf2f(h[(size_t)idx * 64 + lane]);
        }
        atomicAdd(&gsum[g0 * 64 + lane], acc);
        if (lane == 0) atomicAdd(&gcnt[g0], i1 - i0);
    } else {
        int cur = g0;
        float acc = 0.f;
        int cnt = 0;
        for (int i = i0; i < i1; i++) {
            int g = batch[i];
            if (g != cur) {
                atomicAdd(&gsum[cur * 64 + lane], acc);
                if (lane == 0) atomicAdd(&gcnt[cur], cnt);
                acc = 0.f; cnt = 0; cur = g;
            }
            acc += bf2f(h[(size_t)i * 64 + lane]);
            cnt++;
        }
        atomicAdd(&gsum[cur * 64 + lane], acc);
        if (lane == 0) atomicAdd(&gcnt[cur], cnt);
    }
}

// ---------------- Head, stage 1 ----------------

__global__ __launch_bounds__(TPB) void k_head1(const float* __restrict__ gsum,
                                               const int* __restrict__ gcnt,
                                               const float* __restrict__ fc1w,
                                               const float* __restrict__ fc1b,
                                               float* __restrict__ z) {
    int t = threadIdx.x;
    int g = blockIdx.x * 2 + (t >> 7);
    int o = t & 127;
    int c = gcnt[g]; if (c < 1) c = 1;
    float inv = 1.0f / (float)c;
    float a = fc1b[o];
#pragma unroll 16
    for (int j = 0; j < 64; j++) {
        float pj = gsum[g * 64 + j] * inv;
        a += pj * fc1w[j * 128 + o];
    }
    z[g * 128 + o] = fmaxf(a, 0.f);
}

// ---------------- Head, stage 2 ----------------

__global__ __launch_bounds__(TPB) void k_head2(const float* __restrict__ z,
                                               const float* __restrict__ fc2w,
                                               const float* __restrict__ fc2b,
                                               float* __restrict__ out) {
    int t = threadIdx.x;
    int g = t >> 2, c = t & 3;
    float a = fc2b[c];
#pragma unroll 16
    for (int o = 0; o < 128; o++) a += z[g * 128 + o] * fc2w[o * 4 + c];
    out[t] = a;
}

// ---------------- launch ----------------

extern "C" void kernel_launch(void* const* d_in, const int* in_sizes, int n_in,
                              void* d_out, int out_size, void* d_ws, size_t ws_size,
                              hipStream_t stream) {
    const float* x    = (const float*)d_in[0];
    const int*   ei   = (const int*)d_in[1];
    const int*   batch= (const int*)d_in[2];
    const float* W1   = (const float*)d_in[3];
    const float* b1   = (const float*)d_in[4];
    const float* W2   = (const float*)d_in[5];
    const float* b2   = (const float*)d_in[6];
    const float* fc1w = (const float*)d_in[7];
    const float* fc1b = (const float*)d_in[8];
    const float* fc2w = (const float*)d_in[9];
    const float* fc2b = (const float*)d_in[10];

    const int n = in_sizes[2];        // 50000
    const int E = in_sizes[1] / 2;    // 800000
    const int* srcv = ei;
    const int* dstv = ei + E;
    const int nbuck = (n + 255) >> 8; // 196 (must be <= 256)

    // workspace carve; zeroed region contiguous at front
    char* w = (char*)d_ws;
    int*   gcur   = (int*)w;            w += 256 * 4;
    int*   gcnt   = (int*)w;            w += 64 * 4;
    float* gsum   = (float*)w;          w += 64 * 64 * 4;
    size_t zbytes = (size_t)w - (size_t)d_ws;
    int*   csr_off= (int*)w;            w += (size_t)(n + 1) * 4;
    float* dinv   = (float*)w;          w += (size_t)n * 4;
    int*   csr_src= (int*)w;            w += (size_t)E * 4;
    int*   staged = (int*)w;            w += (size_t)nbuck * BCAP * 4;
    float* zbuf   = (float*)w;          w += 64 * 128 * 4;
    w = (char*)(((size_t)w + 255) & ~(size_t)255);
    bfu* hs = (bfu*)w;                  w += (size_t)n * 64 * 2;
    w = (char*)(((size_t)w + 255) & ~(size_t)255);
    bfu* hb = (bfu*)w;                  w += (size_t)n * 64 * 2;

    hipMemsetAsync(d_ws, 0, zbytes, stream);

    int gA = (E + CHUNK_A - 1) / CHUNK_A;   // 196
    k_passA<<<gA, TPB, 0, stream>>>(srcv, dstv, E, gcur, staged, nbuck);
    k_passB<<<nbuck, TPB, 0, stream>>>(staged, gcur, csr_off, csr_src, dinv, n, nbuck);

    int gRows = (n + 127) / 128;
    int gNode = (n + 3) / 4;
    // layer 1 gemm: x*W1*dinv -> hs
    k_gemm<256, false><<<gRows, TPB, 0, stream>>>(x, W1, dinv, hs, n);
    // agg1 + fused gemm2: hs -> (agg,relu,+b1) -> *W2*dinv -> hb
    k_agg<true><<<gNode, TPB, 0, stream>>>(hs, csr_off, csr_src, dinv, b1, W2, hb, n);
    // agg2: hb -> (agg,relu,+b2) -> hs
    k_agg<false><<<gNode, TPB, 0, stream>>>(hb, csr_off, csr_src, dinv, b2, nullptr, hs, n);

    int nwaves16 = (n + 15) / 16;
    k_pool<<<(nwaves16 + 3) / 4, TPB, 0, stream>>>(hs, batch, n, gsum, gcnt);
    k_head1<<<32, TPB, 0, stream>>>(gsum, gcnt, fc1w, fc1b, zbuf);
    k_head2<<<1, TPB, 0, stream>>>(zbuf, fc2w, fc2b, (float*)d_out);
}